// Round 4
// baseline (278.025 us; speedup 1.0000x reference)
//
#include <hip/hip_runtime.h>
#include <cmath>

// Problem constants (from reference)
constexpr int Bn = 32, An = 3, Sn = 80, NCc = 80;
constexpr int NCELL = Bn * An * Sn * Sn;     // 614400
constexpr int BDIM  = 256;
constexpr int NBLK  = 1200;                  // 2 cells per thread: 1200*512 = 614400
constexpr float EPSc = 1e-7f;

__device__ __forceinline__ float rcpf(float x) { return __builtin_amdgcn_rcpf(x); }

// atan(x) for x>0, minimax poly on (0,1] + reflection; |err| < 2e-5
__device__ __forceinline__ float fast_atan_pos(float x) {
    const float inv = rcpf(x);
    const float t  = fminf(x, inv);          // (0,1]
    const float t2 = t * t;
    float p = fmaf(t2, 0.0208351f, -0.0851330f);
    p = fmaf(t2, p, 0.1801410f);
    p = fmaf(t2, p, -0.3302995f);
    p = fmaf(t2, p, 0.9998660f);
    const float a = t * p;
    return (x > 1.f) ? (1.57079632679f - a) : a;
}

// per-cell obj/noobj work (CIoU + both BCE terms); returns tk via ref
__device__ __forceinline__ void cell_work(
    int i, const float* __restrict__ pp, const float* __restrict__ tt,
    float t0, float z0, const float* __restrict__ anchors,
    float& nsum, float& osum, float& bsum, float& ocnt, int& tk, bool& obj)
{
    obj = (t0 == 1.0f);
    if (t0 == 0.0f) {
        nsum += fmaxf(z0, 0.f) + __logf(1.f + __expf(-fabsf(z0)));
    }
    if (obj) {
        const float p1 = pp[1], p2 = pp[2], p3 = pp[3], p4 = pp[4];
        const float px = rcpf(1.f + __expf(-p1));
        const float py = rcpf(1.f + __expf(-p2));
        const int   a  = (i / (Sn * Sn)) % An;
        const float pw = __expf(p3) * anchors[2 * a];
        const float ph = __expf(p4) * anchors[2 * a + 1];
        const float tx = tt[1], ty = tt[2], tw = tt[3], th = tt[4];
        tk = (int)tt[5];

        const float x1a = px - pw * 0.5f, x1b = px + pw * 0.5f;
        const float y1a = py - ph * 0.5f, y1b = py + ph * 0.5f;
        const float x2a = tx - tw * 0.5f, x2b = tx + tw * 0.5f;
        const float y2a = ty - th * 0.5f, y2b = ty + th * 0.5f;

        const float iw = fmaxf(fminf(x1b, x2b) - fmaxf(x1a, x2a), 0.f);
        const float ih = fmaxf(fminf(y1b, y2b) - fmaxf(y1a, y2a), 0.f);
        const float inter = iw * ih;
        const float uni   = pw * ph + tw * th - inter + EPSc;
        const float iou   = inter * rcpf(uni);

        const float cw = fmaxf(x1b, x2b) - fminf(x1a, x2a);
        const float ch = fmaxf(y1b, y2b) - fminf(y1a, y2a);
        const float c2 = cw * cw + ch * ch + EPSc;
        const float rho2 = (tx - px) * (tx - px) + (ty - py) * (ty - py);

        const float fopi2 = 4.0f / (3.14159265358979323846f * 3.14159265358979323846f);
        const float dv = fast_atan_pos(tw * rcpf(th + EPSc))
                       - fast_atan_pos(pw * rcpf(ph + EPSc));
        const float v  = fopi2 * dv * dv;
        const float alpha = v * rcpf(1.f - iou + v + EPSc);
        const float ciou  = iou - rho2 * rcpf(c2) - alpha * v;
        bsum += 1.f - ciou;

        // quirk: BCE-with-logits(sigmoid(z0), 1) = log(1+exp(-s))
        const float s = rcpf(1.f + __expf(-z0));
        osum += __logf(1.f + __expf(-s));
        ocnt += 1.f;
    }
}

// wave-cooperative class CE over the obj lanes of one 64-cell group
__device__ __forceinline__ void class_ce(
    unsigned long long mask, int wbase, int lane, int tk,
    const float* __restrict__ pred, float& csum)
{
    while (mask) {
        const int lj0 = __builtin_ctzll(mask); mask &= mask - 1ull;
        int lj1 = -1;
        if (mask) { lj1 = __builtin_ctzll(mask); mask &= mask - 1ull; }

        const float* pa = pred + (size_t)(wbase + lj0) * 85 + 5;
        const float* pb = (lj1 >= 0) ? (pred + (size_t)(wbase + lj1) * 85 + 5) : pa;
        const float a1 = pa[lane];
        const float a2 = (lane < 16) ? pa[64 + lane] : 0.f;
        const float b1 = pb[lane];
        const float b2 = (lane < 16) ? pb[64 + lane] : 0.f;
        const int ka = __shfl(tk, lj0);
        const int kb = (lj1 >= 0) ? __shfl(tk, lj1) : 0;

        float ea = __expf(a1);
        float ua = 0.00125f * a1 + ((lane == ka) ? 0.9f * a1 : 0.f);
        float eb = __expf(b1);
        float ub = 0.00125f * b1 + ((lane == kb) ? 0.9f * b1 : 0.f);
        if (lane < 16) {
            ea += __expf(a2);
            ua += 0.00125f * a2 + ((64 + lane == ka) ? 0.9f * a2 : 0.f);
            eb += __expf(b2);
            ub += 0.00125f * b2 + ((64 + lane == kb) ? 0.9f * b2 : 0.f);
        }
        #pragma unroll
        for (int off = 32; off; off >>= 1) {   // two independent chains
            ea += __shfl_xor(ea, off);
            ua += __shfl_xor(ua, off);
            eb += __shfl_xor(eb, off);
            ub += __shfl_xor(ub, off);
        }
        float ce = __logf(ea) - ua;
        if (lj1 >= 0) ce += __logf(eb) - ub;
        if (lane == 0) csum += ce;
    }
}

__global__ __launch_bounds__(BDIM) void yolo_main(
    const float* __restrict__ pred, const float* __restrict__ target,
    const float* __restrict__ anchors, float* __restrict__ partials)
{
    const int lane = threadIdx.x & 63;
    const int wv   = threadIdx.x >> 6;
    const int base = blockIdx.x * 512;
    const int iA   = base + threadIdx.x;        // cells [base, base+256)
    const int iB   = iA + 256;                  // cells [base+256, base+512)

    const float* ttA = target + (size_t)iA * 6;
    const float* ppA = pred   + (size_t)iA * 85;
    const float* ttB = target + (size_t)iB * 6;
    const float* ppB = pred   + (size_t)iB * 85;

    // issue all four front loads before any use (2x MLP vs 1-cell/thread)
    const float t0A = ttA[0];
    const float z0A = ppA[0];
    const float t0B = ttB[0];
    const float z0B = ppB[0];

    float nsum = 0.f, osum = 0.f, bsum = 0.f, ocnt = 0.f, csum = 0.f;
    int tkA = 0, tkB = 0;
    bool objA, objB;

    cell_work(iA, ppA, ttA, t0A, z0A, anchors, nsum, osum, bsum, ocnt, tkA, objA);
    cell_work(iB, ppB, ttB, t0B, z0B, anchors, nsum, osum, bsum, ocnt, tkB, objB);

    class_ce(__ballot(objA), base + wv * 64,        lane, tkA, pred, csum);
    class_ce(__ballot(objB), base + 256 + wv * 64,  lane, tkB, pred, csum);

    // ---- wave butterfly of the 5 accumulators ----
    #pragma unroll
    for (int off = 32; off; off >>= 1) {
        nsum += __shfl_xor(nsum, off);
        osum += __shfl_xor(osum, off);
        bsum += __shfl_xor(bsum, off);
        csum += __shfl_xor(csum, off);
        ocnt += __shfl_xor(ocnt, off);
    }

    __shared__ float red[4][5];
    if (lane == 0) {
        red[wv][0] = nsum; red[wv][1] = osum; red[wv][2] = bsum;
        red[wv][3] = csum; red[wv][4] = ocnt;
    }
    __syncthreads();
    if (threadIdx.x < 5) {
        const int j = threadIdx.x;
        partials[(size_t)blockIdx.x * 8 + j] =
            red[0][j] + red[1][j] + red[2][j] + red[3][j];
    }
}

__global__ __launch_bounds__(256) void yolo_finish(
    const float* __restrict__ partials, float* __restrict__ out)
{
    float s[5] = {0.f, 0.f, 0.f, 0.f, 0.f};
    for (int b = threadIdx.x; b < NBLK; b += 256) {
        #pragma unroll
        for (int j = 0; j < 5; ++j) s[j] += partials[(size_t)b * 8 + j];
    }
    #pragma unroll
    for (int off = 32; off; off >>= 1) {
        #pragma unroll
        for (int j = 0; j < 5; ++j) s[j] += __shfl_xor(s[j], off);
    }
    __shared__ float red[4][5];
    const int wv = threadIdx.x >> 6, lane = threadIdx.x & 63;
    if (lane == 0) {
        #pragma unroll
        for (int j = 0; j < 5; ++j) red[wv][j] = s[j];
    }
    __syncthreads();
    if (threadIdx.x == 0) {
        float n[5];
        #pragma unroll
        for (int j = 0; j < 5; ++j)
            n[j] = red[0][j] + red[1][j] + red[2][j] + red[3][j];
        const float M  = n[4];
        const float fM = fmaxf(M, 1.f);
        const float noobj_l = n[0] / fmaxf((float)NCELL - M, 1.f);
        const float obj_l   = n[1] / fM;
        const float box_l   = n[2] / fM;
        const float cls_l   = n[3] / fM;
        out[0] = 2.f * box_l + obj_l + noobj_l + cls_l;
    }
}

extern "C" void kernel_launch(void* const* d_in, const int* in_sizes, int n_in,
                              void* d_out, int out_size, void* d_ws, size_t ws_size,
                              hipStream_t stream) {
    const float* pred    = (const float*)d_in[0];
    const float* target  = (const float*)d_in[1];
    const float* anchors = (const float*)d_in[2];
    float* out = (float*)d_out;
    float* partials = (float*)d_ws;   // 1200 * 8 floats, all written before read

    yolo_main<<<NBLK, BDIM, 0, stream>>>(pred, target, anchors, partials);
    yolo_finish<<<1, 256, 0, stream>>>(partials, out);
}